// Round 3
// baseline (459.155 us; speedup 1.0000x reference)
//
#include <hip/hip_runtime.h>

// ParallelTransport: out[e,c,:] = R(rho[e]) @ x[row[e], c, :]
// R = [[c,-s],[s,c]]; layout (...,C,2): consecutive f32 pairs.
// Dtypes: x f32, edge_index int32 (harness-converted), rho f32, out f32.
//
// Timed window includes a harness re-poison fill (~264 us, writes 1.6 GB) --
// kernel-only time is dur_us - ~264. Kernel is gather-latency exposed:
// row[e] -> x[row] is a 2-deep dependent chain. This version processes TWO
// independent edges per thread (e0 and e0+E/2) to double MLP: both row/rho
// loads issue, then all four 128B x-line gathers, before compute/stores.
//
// Access shape per 8-lane edge-group: thread k covers bytes [k*16,k*16+16)
// of each of the row's two 128B cache lines -> every load/store instruction
// is a set of fully-dense 128B lines.
//
// out (410 MB) is a pure write stream -> nontemporal stores keep it from
// evicting x (12.8 MB, ~32x gather reuse) out of the 4 MB per-XCD L2s.

typedef float v4f __attribute__((ext_vector_type(4)));

__device__ __forceinline__ float2 rot_pair(float p0, float p1, float c, float s) {
    float2 y;
    y.x = fmaf(c, p0, -(s * p1));   // c*p0 - s*p1
    y.y = fmaf(s, p0,  c * p1);     // s*p0 + c*p1
    return y;
}

__global__ __launch_bounds__(256) void ParallelTransport_kernel(
    const float* __restrict__ x,      // (N, 32, 2) = N*64 f32
    const int*   __restrict__ row,    // edge_index[0], E int32
    const float* __restrict__ rho,    // E f32
    float*       __restrict__ out,    // (E, 32, 2) = E*64 f32
    int E, int EH)                    // EH = ceil(E/2)
{
    int t  = blockIdx.x * blockDim.x + threadIdx.x;
    int e0 = t >> 3;          // edge in first half
    int k  = t & 7;           // 16B chunk index within a 128B half-row
    if (e0 >= EH) return;
    int e1 = e0 + EH;
    bool has1 = (e1 < E);

    // --- issue both scalar streams ---
    int   r0   = __builtin_nontemporal_load(row + e0);
    float ang0 = __builtin_nontemporal_load(rho + e0);
    int   r1   = has1 ? __builtin_nontemporal_load(row + e1) : 0;
    float ang1 = has1 ? __builtin_nontemporal_load(rho + e1) : 0.0f;

    // --- issue all four gather lines (independent chains) ---
    const float* s0f = x + ((size_t)r0 << 6) + (k << 2);
    const float* s1f = x + ((size_t)r1 << 6) + (k << 2);
    v4f a0 = *reinterpret_cast<const v4f*>(s0f);
    v4f b0 = *reinterpret_cast<const v4f*>(s0f + 32);
    v4f a1 = *reinterpret_cast<const v4f*>(s1f);
    v4f b1 = *reinterpret_cast<const v4f*>(s1f + 32);

    float sn0, cs0, sn1, cs1;
    __sincosf(ang0, &sn0, &cs0);
    __sincosf(ang1, &sn1, &cs1);

    // --- edge 0 ---
    {
        float2 p0 = rot_pair(a0.x, a0.y, cs0, sn0);
        float2 p1 = rot_pair(a0.z, a0.w, cs0, sn0);
        float2 p2 = rot_pair(b0.x, b0.y, cs0, sn0);
        float2 p3 = rot_pair(b0.z, b0.w, cs0, sn0);
        float* dstf = out + ((size_t)e0 << 6) + (k << 2);
        v4f o0 = {p0.x, p0.y, p1.x, p1.y};
        v4f o1 = {p2.x, p2.y, p3.x, p3.y};
        __builtin_nontemporal_store(o0, reinterpret_cast<v4f*>(dstf));
        __builtin_nontemporal_store(o1, reinterpret_cast<v4f*>(dstf + 32));
    }
    // --- edge 1 ---
    if (has1) {
        float2 p0 = rot_pair(a1.x, a1.y, cs1, sn1);
        float2 p1 = rot_pair(a1.z, a1.w, cs1, sn1);
        float2 p2 = rot_pair(b1.x, b1.y, cs1, sn1);
        float2 p3 = rot_pair(b1.z, b1.w, cs1, sn1);
        float* dstf = out + ((size_t)e1 << 6) + (k << 2);
        v4f o0 = {p0.x, p0.y, p1.x, p1.y};
        v4f o1 = {p2.x, p2.y, p3.x, p3.y};
        __builtin_nontemporal_store(o0, reinterpret_cast<v4f*>(dstf));
        __builtin_nontemporal_store(o1, reinterpret_cast<v4f*>(dstf + 32));
    }
}

extern "C" void kernel_launch(void* const* d_in, const int* in_sizes, int n_in,
                              void* d_out, int out_size, void* d_ws, size_t ws_size,
                              hipStream_t stream) {
    const float* x   = (const float*)d_in[0];
    const int*   ei  = (const int*)d_in[1];    // (2,E) int32; row = first E
    const float* rho = (const float*)d_in[2];
    float*       out = (float*)d_out;

    const int E  = in_sizes[2];                // rho element count
    const int EH = (E + 1) / 2;
    const int threads = EH * 8;
    const int block = 256;
    const int grid = (threads + block - 1) / block;

    ParallelTransport_kernel<<<grid, block, 0, stream>>>(x, ei, rho, out, E, EH);
}